// Round 16
// baseline (53.220 us; speedup 1.0000x reference)
//
#include <hip/hip_runtime.h>
#include <hip/hip_bf16.h>

typedef __attribute__((ext_vector_type(8))) short s16x8;
typedef __attribute__((ext_vector_type(4))) short s16x4;
typedef __attribute__((ext_vector_type(4))) float fx4;

#define DEVINL __device__ __forceinline__

constexpr int EMBED = 768;
constexpr int HD    = 64;
constexpr int NB    = 16;
constexpr int LEN   = 1024;
constexpr int M_TOT = NB * LEN;   // 16384
constexpr int KVQ   = LEN / 4;    // 256 kv per group in fused attn
constexpr int WELEM = HD * EMBED; // 49152

// fp32 -> bf16 RNE via v_cvt_pk_bf16_f32 (2 elems/inst).
DEVINL unsigned pk2(float lo, float hi) {
  __hip_bfloat162 h = __float22bfloat162_rn(float2{lo, hi});
  union { __hip_bfloat162 h; unsigned u; } c; c.h = h;
  return c.u;
}
DEVINL s16x8 cvt8(fx4 a, fx4 b) {
  union { unsigned u[4]; s16x8 v; } r;
  r.u[0] = pk2(a[0], a[1]); r.u[1] = pk2(a[2], a[3]);
  r.u[2] = pk2(b[0], b[1]); r.u[3] = pk2(b[2], b[3]);
  return r.v;
}
DEVINL s16x4 cvt4(float a0, float a1, float a2, float a3) {
  union { unsigned u[2]; s16x4 v; } r;
  r.u[0] = pk2(a0, a1); r.u[1] = pk2(a2, a3);
  return r.v;
}
DEVINL s16x4 cvt4v(fx4 a) { return cvt4(a[0], a[1], a[2], a[3]); }

DEVINL fx4 mfma16(s16x8 a, s16x8 b, fx4 c) {
  return __builtin_amdgcn_mfma_f32_16x16x32_bf16(a, b, c, 0, 0, 0);
}

// async global->LDS DMA, 16B/lane; LDS dest = wave-uniform base + lane*16,
// global source = per-lane (enables source-side swizzle, m173 pattern).
DEVINL void gload16(const void* g, void* l) {
  __builtin_amdgcn_global_load_lds(
      (const __attribute__((address_space(1))) void*)g,
      (__attribute__((address_space(3))) void*)l, 16, 0, 0);
}

// ---------------------------------------------------------------------------
// One-shot: convert Wq|Wk|Wv (each 64x768 fp32) to bf16, packed [3][49152].
// ---------------------------------------------------------------------------
__global__ __launch_bounds__(256) void convert_w_kernel(
    const float* __restrict__ a, const float* __restrict__ b,
    const float* __restrict__ c, short* __restrict__ out)
{
  const int gid = blockIdx.x * 256 + threadIdx.x;   // 18432 threads, 8 elem each
  const int seg = gid / (WELEM / 8);
  const int off = (gid % (WELEM / 8)) * 8;
  const float* src = (seg == 0) ? a : (seg == 1) ? b : c;
  fx4 v0 = *reinterpret_cast<const fx4*>(src + off);
  fx4 v1 = *reinterpret_cast<const fx4*>(src + off + 4);
  *reinterpret_cast<s16x8*>(out + (size_t)seg * WELEM + off) = cvt8(v0, v1);
}

// ---------------------------------------------------------------------------
// Round-16 KV-projection ONLY (Q moved into attn). r11 schedule (the best
// measured), with: 1024-thr/16-wave blocks (highest measured staging rate),
// BK=64 -> only 12 steps (halves the per-step drain count), grid 256
// (BM=64). Staged bytes: enc 48 MB + Wk/Wv 48 MB = 96 MB (vs 168 in r11).
// Per step per wave: exactly 2 gload16. Wave w: mg=w>>2 (m-group),
// nq=w&3 (n-quadrant); 4 MFMA/step. Source-XOR swizzles as r11/r15.
// LDS: dbuf x (X 16KB fp32 + Wk 8KB + Wv 8KB) = 64 KB.
// ---------------------------------------------------------------------------
__global__ __launch_bounds__(1024, 1) void proj_kv_kernel(
    const float* __restrict__ enc,
    const short* __restrict__ Wk, const short* __restrict__ Wv,
    const float* __restrict__ bk, const float* __restrict__ bv,
    short* __restrict__ Kout, short* __restrict__ VT)
{
  constexpr int NST   = 12;
  constexpr int BUFSZ = 32768;   // X 16384 @0, Wk 8192 @16384, Wv 8192 @24576
  __shared__ __align__(16) char smem[65536];

  const int t = threadIdx.x, lane = t & 63, w = t >> 6;   // w = 0..15
  const int fr = lane & 15, fg = lane >> 4;
  const int m0 = blockIdx.x * 64;
  const char* Xg = (const char*)(enc + (size_t)m0 * EMBED);

  // staging role: waves 0-7 -> X (2KB each), 8-11 -> Wk, 12-15 -> Wv
  int src0, src1, dst0, dst1, kmul;
  const char* gb;
  if (w < 8) {
    const int p0 = w * 2048 + lane * 16, p1 = p0 + 1024;
    const int r0 = p0 >> 8, c0 = p0 & 255;
    const int r1 = p1 >> 8, c1 = p1 & 255;
    src0 = r0 * 3072 + (c0 ^ ((r0 & 7) << 4));
    src1 = r1 * 3072 + (c1 ^ ((r1 & 7) << 4));
    dst0 = p0; dst1 = p1; kmul = 256; gb = Xg;
  } else {
    const int base = (w < 12) ? 16384 : 24576;
    gb = (const char*)((w < 12) ? Wk : Wv);
    const int p0 = (w & 3) * 2048 + lane * 16, p1 = p0 + 1024;
    const int r0 = p0 >> 7, c0 = p0 & 127;
    const int r1 = p1 >> 7, c1 = p1 & 127;
    src0 = r0 * 1536 + (c0 ^ ((r0 & 7) << 4));
    src1 = r1 * 1536 + (c1 ^ ((r1 & 7) << 4));
    dst0 = base + p0; dst1 = base + p1; kmul = 128;
  }

  auto stage = [&](int k) {
    char* buf = smem + (k & 1) * BUFSZ;
    gload16(gb + k * kmul + src0, buf + dst0);
    gload16(gb + k * kmul + src1, buf + dst1);
  };

  const int mg = w >> 2, nq = w & 3;
  fx4 aK = fx4{0.f, 0.f, 0.f, 0.f};
  fx4 aV = fx4{0.f, 0.f, 0.f, 0.f};
  const int xsw = (fr & 7) << 4;            // (mg*16+fr)&7 == fr&7
  const int wr  = nq * 16 + fr;
  const int wsw = (fr & 7) << 4;            // wr&7 == fr&7

  auto compute = [&](int k) {
    const char* cur = smem + (k & 1) * BUFSZ;
    const char* xrb = cur + (mg * 16 + fr) * 256;
#pragma unroll
    for (int ks = 0; ks < 2; ++ks) {
      fx4 xlo = *reinterpret_cast<const fx4*>(xrb + ((ks * 128 + fg * 32) ^ xsw));
      fx4 xhi = *reinterpret_cast<const fx4*>(xrb + ((ks * 128 + fg * 32 + 16) ^ xsw));
      s16x8 xa = cvt8(xlo, xhi);
      const int wo = wr * 128 + ((ks * 64 + fg * 16) ^ wsw);
      s16x8 wfk = *reinterpret_cast<const s16x8*>(cur + 16384 + wo);
      s16x8 wfv = *reinterpret_cast<const s16x8*>(cur + 24576 + wo);
      aK = mfma16(wfk, xa, aK);
      aV = mfma16(wfv, xa, aV);
    }
  };

  stage(0);
  __syncthreads();
#pragma unroll 2
  for (int k = 0; k < NST; ++k) {
    if (k + 1 < NST) stage(k + 1);
    compute(k);
    __syncthreads();
  }

  // epilogue: D[n][m]: n = nq*16+fg*4+r, m = m0 + mg*16 + fr
  const int m  = m0 + mg * 16 + fr;
  const int n0 = nq * 16 + fg * 4;
  fx4 bk4 = *reinterpret_cast<const fx4*>(bk + n0);
  *reinterpret_cast<s16x4*>(Kout + (size_t)m * HD + n0) =
      cvt4(aK[0] + bk4[0], aK[1] + bk4[1], aK[2] + bk4[2], aK[3] + bk4[3]);
  fx4 bv4 = *reinterpret_cast<const fx4*>(bv + n0);
  const int bidx = m0 >> 10;                 // 64 | 1024: no batch straddle
  const int kvp  = (m0 & 1023) + mg * 16 + fr;
#pragma unroll
  for (int r = 0; r < 4; ++r)
    VT[((size_t)(bidx * HD + n0 + r)) * LEN + kvp] =
        (short)pk2(aV[r] + bv4[r], 0.f);
}

// ---------------------------------------------------------------------------
// Fused Q-projection + flash attention. Block = (batch, 64 q-rows), 1024 thr.
// Phase 0: stage dec rows -> bf16 LDS (one coalesced burst); 16 waves each
//   MFMA a 16x16 Q-subtile (Wq streamed from L2 with 1-step register
//   prefetch); Q -> LDS; read qa fragments. Q never touches HBM.
// Phase 1: existing attn loop (4 KV-groups x 4 q-waves, lane-local softmax,
//   LDS-staged K/V, partial combine via overlay) — unchanged.
// LDS overlays (phase-ordered, barriers between):
//   P0: Xq [64][776] bf16 @0 (99328), Qls [64][72] @99328 (9216)
//   P1: Kls@0, Vls@36864, Plds@73728, then HL/ML combine overlay.
// ---------------------------------------------------------------------------
__global__ __launch_bounds__(1024, 4) void attn_kernel(
    const float* __restrict__ dec, const short* __restrict__ Wq,
    const float* __restrict__ bq,
    const short* __restrict__ K, const short* __restrict__ VT,
    float* __restrict__ Out)
{
  __shared__ __align__(16) char smem[110592];
  short (*Xq)[776]      = reinterpret_cast<short(*)[776]>(smem);
  short (*Qls)[72]      = reinterpret_cast<short(*)[72]>(smem + 99328);
  short (*Kls)[64][72]  = reinterpret_cast<short(*)[64][72]>(smem);
  short (*Vls)[64][72]  = reinterpret_cast<short(*)[64][72]>(smem + 36864);
  short (*Plds)[16][72] = reinterpret_cast<short(*)[16][72]>(smem + 73728);
  float (*HL)[64][68]   = reinterpret_cast<float(*)[64][68]>(smem);
  float2 (*ML)[64]      = reinterpret_cast<float2(*)[64]>(smem + 69632);

  const int t = threadIdx.x, lane = t & 63, w = t >> 6;
  const int g = w >> 2, wl = w & 3;
  const int fr = lane & 15, fg = lane >> 4;
  const int xcd = blockIdx.x & 7;
  const int idx = blockIdx.x >> 3;        // 0..31
  const int b   = xcd + ((idx & 1) << 3);
  const int q0  = (idx >> 1) * 64;

  // ---- phase 0: Q projection for this block's 64 q-rows ----
  {
    const int xrow = t >> 4, sc4 = (t & 15) * 4;
    const float* xr = dec + ((size_t)b * LEN + q0 + xrow) * EMBED + sc4;
#pragma unroll
    for (int i = 0; i < 12; ++i) {
      fx4 v = *reinterpret_cast<const fx4*>(xr + i * 64);
      *reinterpret_cast<s16x4*>(&Xq[xrow][i * 64 + sc4]) = cvt4v(v);
    }
  }
  __syncthreads();
  {
    // wave (g,wl): Q-subtile rows wl*16.., cols g*16..; W from L2 w/ prefetch
    const short* wqf = Wq + (size_t)(g * 16 + fr) * EMBED + fg * 8;
    fx4 acc = fx4{0.f, 0.f, 0.f, 0.f};
    s16x8 wfc = *reinterpret_cast<const s16x8*>(wqf);
#pragma unroll
    for (int k = 0; k < 24; ++k) {
      s16x8 wfn;
      if (k < 23) wfn = *reinterpret_cast<const s16x8*>(wqf + (k + 1) * 32);
      s16x8 xa = *reinterpret_cast<const s16x8*>(&Xq[wl * 16 + fr][k * 32 + fg * 8]);
      acc = mfma16(wfc, xa, acc);
      if (k < 23) wfc = wfn;
    }
    fx4 bb = *reinterpret_cast<const fx4*>(bq + g * 16 + fg * 4);
    *reinterpret_cast<s16x4*>(&Qls[wl * 16 + fr][g * 16 + fg * 4]) =
        cvt4(acc[0] + bb[0], acc[1] + bb[1], acc[2] + bb[2], acc[3] + bb[3]);
  }
  __syncthreads();
  s16x8 qa0 = *reinterpret_cast<const s16x8*>(&Qls[wl * 16 + fr][fg * 8]);
  s16x8 qa1 = *reinterpret_cast<const s16x8*>(&Qls[wl * 16 + fr][32 + fg * 8]);

  // ---- phase 1: attention (K/V from proj_kv outputs) ----
  const short* Kb  = K  + ((size_t)b * LEN + g * KVQ) * HD;
  const short* VTb = VT + (size_t)b * HD * LEN + g * KVQ;

  const int u = t & 255;
  const int srow = u >> 2;          // 0..63
  const int sch  = (u & 3) * 16;    // short col offset: 0,16,32,48

  // issue K/V tile-0 loads while Qls reads drain
  s16x8 pk0 = *reinterpret_cast<const s16x8*>(Kb + (size_t)srow * HD + sch);
  s16x8 pk1 = *reinterpret_cast<const s16x8*>(Kb + (size_t)srow * HD + sch + 8);
  s16x8 pv0 = *reinterpret_cast<const s16x8*>(VTb + (size_t)srow * LEN + sch);
  s16x8 pv1 = *reinterpret_cast<const s16x8*>(VTb + (size_t)srow * LEN + sch + 8);
  __syncthreads();   // all qa/Qls reads done -> Kls/Vls/Plds regions free

  fx4 hacc[4];
#pragma unroll
  for (int c = 0; c < 4; ++c) hacc[c] = fx4{0.f, 0.f, 0.f, 0.f};
  float mrun = -1e30f, lsum = 0.f;
  const float SC = 0.125f * 1.44269504088896340736f;  // 1/sqrt(64) * log2(e)

  *reinterpret_cast<s16x8*>(&Kls[g][srow][sch])     = pk0;
  *reinterpret_cast<s16x8*>(&Kls[g][srow][sch + 8]) = pk1;
  *reinterpret_cast<s16x8*>(&Vls[g][srow][sch])     = pv0;
  *reinterpret_cast<s16x8*>(&Vls[g][srow][sch + 8]) = pv1;
  __syncthreads();

#pragma unroll
  for (int it = 0; it < KVQ / 64; ++it) {
    if (it + 1 < KVQ / 64) {  // issue next tile's loads before compute
      const int nk = (it + 1) * 64;
      pk0 = *reinterpret_cast<const s16x8*>(Kb + (size_t)(nk + srow) * HD + sch);
      pk1 = *reinterpret_cast<const s16x8*>(Kb + (size_t)(nk + srow) * HD + sch + 8);
      pv0 = *reinterpret_cast<const s16x8*>(VTb + (size_t)srow * LEN + nk + sch);
      pv1 = *reinterpret_cast<const s16x8*>(VTb + (size_t)srow * LEN + nk + sch + 8);
    }
    fx4 sacc[4];
#pragma unroll
    for (int s = 0; s < 4; ++s) {
      s16x8 kf0 = *reinterpret_cast<const s16x8*>(&Kls[g][s * 16 + fr][fg * 8]);
      s16x8 kf1 = *reinterpret_cast<const s16x8*>(&Kls[g][s * 16 + fr][32 + fg * 8]);
      fx4 z = fx4{0.f, 0.f, 0.f, 0.f};
      z = mfma16(kf0, qa0, z);
      sacc[s] = mfma16(kf1, qa1, z);
    }
    float xs[4][4];
    float xm = -1e30f;
#pragma unroll
    for (int s = 0; s < 4; ++s)
#pragma unroll
      for (int r = 0; r < 4; ++r) {
        xs[s][r] = sacc[s][r] * SC;
        xm = fmaxf(xm, xs[s][r]);
      }
    xm = fmaxf(xm, __shfl_xor(xm, 16, 64));
    xm = fmaxf(xm, __shfl_xor(xm, 32, 64));
    const float mn = fmaxf(mrun, xm);
    const float corr = __builtin_amdgcn_exp2f(mrun - mn);
    mrun = mn;
    float ps = 0.f;
#pragma unroll
    for (int s = 0; s < 4; ++s) {
      float p[4];
#pragma unroll
      for (int r = 0; r < 4; ++r) {
        p[r] = __builtin_amdgcn_exp2f(xs[s][r] - mn);
        ps += p[r];
      }
      *reinterpret_cast<s16x4*>(&Plds[w][fr][s * 16 + fg * 4]) =
          cvt4(p[0], p[1], p[2], p[3]);
    }
    ps += __shfl_xor(ps, 16, 64);
    ps += __shfl_xor(ps, 32, 64);
    lsum = lsum * corr + ps;
    __builtin_amdgcn_wave_barrier();
    s16x8 pa0 = *reinterpret_cast<const s16x8*>(&Plds[w][fr][fg * 8]);
    s16x8 pa1 = *reinterpret_cast<const s16x8*>(&Plds[w][fr][32 + fg * 8]);
#pragma unroll
    for (int c = 0; c < 4; ++c) {
      s16x8 vf0 = *reinterpret_cast<const s16x8*>(&Vls[g][c * 16 + fr][fg * 8]);
      s16x8 vf1 = *reinterpret_cast<const s16x8*>(&Vls[g][c * 16 + fr][32 + fg * 8]);
      fx4 h = hacc[c];
#pragma unroll
      for (int r = 0; r < 4; ++r) h[r] *= corr;
      h = mfma16(vf0, pa0, h);
      hacc[c] = mfma16(vf1, pa1, h);
    }
    __syncthreads();  // all waves done reading tile it
    if (it + 1 < KVQ / 64) {
      *reinterpret_cast<s16x8*>(&Kls[g][srow][sch])     = pk0;
      *reinterpret_cast<s16x8*>(&Kls[g][srow][sch + 8]) = pk1;
      *reinterpret_cast<s16x8*>(&Vls[g][srow][sch])     = pv0;
      *reinterpret_cast<s16x8*>(&Vls[g][srow][sch + 8]) = pv1;
    }
    __syncthreads();  // tile it+1 visible
  }
#pragma unroll
  for (int c = 0; c < 4; ++c)
    *reinterpret_cast<fx4*>(&HL[g][wl * 16 + fr][c * 16 + fg * 4]) = hacc[c];
  if (fg == 0) ML[g][wl * 16 + fr] = make_float2(mrun, lsum);
  __syncthreads();
  const int row = t >> 4, d0 = (t & 15) * 4;
  const float2 s0 = ML[0][row], s1 = ML[1][row], s2 = ML[2][row], s3 = ML[3][row];
  const float mm = fmaxf(fmaxf(s0.x, s1.x), fmaxf(s2.x, s3.x));
  const float w0 = __builtin_amdgcn_exp2f(s0.x - mm);
  const float w1 = __builtin_amdgcn_exp2f(s1.x - mm);
  const float w2 = __builtin_amdgcn_exp2f(s2.x - mm);
  const float w3 = __builtin_amdgcn_exp2f(s3.x - mm);
  const float inv = 1.0f / (s0.y * w0 + s1.y * w1 + s2.y * w2 + s3.y * w3);
  fx4 h0 = *reinterpret_cast<const fx4*>(&HL[0][row][d0]);
  fx4 h1 = *reinterpret_cast<const fx4*>(&HL[1][row][d0]);
  fx4 h2 = *reinterpret_cast<const fx4*>(&HL[2][row][d0]);
  fx4 h3 = *reinterpret_cast<const fx4*>(&HL[3][row][d0]);
  fx4 o;
#pragma unroll
  for (int r = 0; r < 4; ++r)
    o[r] = (h0[r] * w0 + h1[r] * w1 + h2[r] * w2 + h3[r] * w3) * inv;
  *reinterpret_cast<fx4*>(Out + ((size_t)b * LEN + q0 + row) * HD + d0) = o;
}

extern "C" void kernel_launch(void* const* d_in, const int* in_sizes, int n_in,
                              void* d_out, int out_size, void* d_ws, size_t ws_size,
                              hipStream_t stream) {
  const float* dec = (const float*)d_in[0];
  const float* enc = (const float*)d_in[1];
  const float* Wq  = (const float*)d_in[2];
  const float* bq  = (const float*)d_in[3];
  const float* Wk  = (const float*)d_in[4];
  const float* bk  = (const float*)d_in[5];
  const float* Wv  = (const float*)d_in[6];
  const float* bv  = (const float*)d_in[7];
  float* out = (float*)d_out;

  short* kws  = (short*)d_ws;                        // [16384,64] bf16
  short* vtws = kws + (size_t)M_TOT * HD;            // [16,64,1024] bf16
  short* wbuf = vtws + (size_t)NB * HD * LEN;        // [3][49152] bf16 weights

  convert_w_kernel<<<(3 * WELEM / 8) / 256, 256, 0, stream>>>(Wq, Wk, Wv, wbuf);
  proj_kv_kernel<<<M_TOT / 64, 1024, 0, stream>>>(
      enc, wbuf + WELEM, wbuf + 2 * (size_t)WELEM, bk, bv, kws, vtws);
  attn_kernel<<<NB * (LEN / 64), 1024, 0, stream>>>(
      dec, wbuf, bq, kws, vtws, out);
}

// Round 17
// 40.158 us; speedup vs baseline: 1.3252x; 1.3252x over previous
//
#include <hip/hip_runtime.h>
#include <hip/hip_bf16.h>

typedef __attribute__((ext_vector_type(8))) short s16x8;
typedef __attribute__((ext_vector_type(4))) short s16x4;
typedef __attribute__((ext_vector_type(4))) float fx4;

#define DEVINL __device__ __forceinline__

constexpr int EMBED = 768;
constexpr int HD    = 64;
constexpr int NB    = 16;
constexpr int LEN   = 1024;
constexpr int M_TOT = NB * LEN;   // 16384
constexpr int KVQ   = LEN / 4;    // 256 kv per group in fused attn
constexpr int WELEM = HD * EMBED; // 49152

// fp32 -> bf16 RNE via v_cvt_pk_bf16_f32 (2 elems/inst).
DEVINL unsigned pk2(float lo, float hi) {
  __hip_bfloat162 h = __float22bfloat162_rn(float2{lo, hi});
  union { __hip_bfloat162 h; unsigned u; } c; c.h = h;
  return c.u;
}
DEVINL s16x8 cvt8(fx4 a, fx4 b) {
  union { unsigned u[4]; s16x8 v; } r;
  r.u[0] = pk2(a[0], a[1]); r.u[1] = pk2(a[2], a[3]);
  r.u[2] = pk2(b[0], b[1]); r.u[3] = pk2(b[2], b[3]);
  return r.v;
}
DEVINL s16x4 cvt4(float a0, float a1, float a2, float a3) {
  union { unsigned u[2]; s16x4 v; } r;
  r.u[0] = pk2(a0, a1); r.u[1] = pk2(a2, a3);
  return r.v;
}

DEVINL fx4 mfma16(s16x8 a, s16x8 b, fx4 c) {
  return __builtin_amdgcn_mfma_f32_16x16x32_bf16(a, b, c, 0, 0, 0);
}

// async global->LDS DMA, 16B/lane; LDS dest = wave-uniform base + lane*16,
// global source = per-lane (enables source-side swizzle, m173 pattern).
DEVINL void gload16(const void* g, void* l) {
  __builtin_amdgcn_global_load_lds(
      (const __attribute__((address_space(1))) void*)g,
      (__attribute__((address_space(3))) void*)l, 16, 0, 0);
}

// ---------------------------------------------------------------------------
// One-shot: convert Wq|Wk|Wv (each 64x768 fp32) to bf16, packed [3][49152].
// ---------------------------------------------------------------------------
__global__ __launch_bounds__(256) void convert_w_kernel(
    const float* __restrict__ a, const float* __restrict__ b,
    const float* __restrict__ c, short* __restrict__ out)
{
  const int gid = blockIdx.x * 256 + threadIdx.x;   // 18432 threads, 8 elem each
  const int seg = gid / (WELEM / 8);
  const int off = (gid % (WELEM / 8)) * 8;
  const float* src = (seg == 0) ? a : (seg == 1) ? b : c;
  fx4 v0 = *reinterpret_cast<const fx4*>(src + off);
  fx4 v1 = *reinterpret_cast<const fx4*>(src + off + 4);
  *reinterpret_cast<s16x8*>(out + (size_t)seg * WELEM + off) = cvt8(v0, v1);
}

// ---------------------------------------------------------------------------
// Round-17 projection: the r16 proj_kv structure (measured ~11-12 us for
// K+V by subtraction — 3x faster than every r11-r15 variant) applied to BOTH
// projections in ONE dispatch. Winning recipe: 1024-thr/16-wave blocks,
// 1 block/CU, BK=64 -> 12 steps, ONLY 1-2 gload16 per wave per step,
// plain __syncthreads loop.
//   grid 512: blocks [0,256) = Q from dec; [256,512) = K,V^T from enc.
//   Staging roles (Q):  waves 0-7 X x2, waves 8-15 Wq x1.
//   Staging roles (KV): waves 0-7 X x2, 8-11 Wk x2, 12-15 Wv x2.
//   Compute: wave (mg=w>>2, nq=w&3): 2 (Q) / 4 (KV) MFMA per step.
//   Source-XOR swizzles (verified r16 refcheck): X rows 256B pitch key
//   (row&7)<<4; W rows 128B pitch key (row&7)<<4.
// LDS: dbuf x (X 16KB + W1 8KB + W2 8KB) = 64 KB.
// ---------------------------------------------------------------------------
template <bool ISQ>
DEVINL void proj_body(const float* __restrict__ X,
                      const short* __restrict__ W1, const short* __restrict__ W2,
                      const float* __restrict__ b1, const float* __restrict__ b2,
                      short* __restrict__ O1, short* __restrict__ VT,
                      int m0, char* smem)
{
  constexpr int NST   = 12;
  constexpr int BUFSZ = 32768;   // X 16384 @0, W1 8192 @16384, W2 8192 @24576
  const int t = threadIdx.x, lane = t & 63, w = t >> 6;   // w = 0..15
  const int fr = lane & 15, fg = lane >> 4;
  const char* Xg = (const char*)(X + (size_t)m0 * EMBED);

  // staging roles
  int src0 = 0, src1 = 0, dst0 = 0, dst1 = 0, kmul = 0, nld = 1;
  const char* gb;
  if (w < 8) {
    const int p0 = w * 2048 + lane * 16, p1 = p0 + 1024;
    const int r0 = p0 >> 8, c0 = p0 & 255;
    const int r1 = p1 >> 8, c1 = p1 & 255;
    src0 = r0 * 3072 + (c0 ^ ((r0 & 7) << 4));
    src1 = r1 * 3072 + (c1 ^ ((r1 & 7) << 4));
    dst0 = p0; dst1 = p1; kmul = 256; gb = Xg; nld = 2;
  } else if (ISQ) {
    const int p0 = (w - 8) * 1024 + lane * 16;   // 8 KB W tile, 1 instr/wave
    const int r0 = p0 >> 7, c0 = p0 & 127;
    src0 = r0 * 1536 + (c0 ^ ((r0 & 7) << 4));
    dst0 = 16384 + p0; kmul = 128; gb = (const char*)W1; nld = 1;
  } else {
    const int base = (w < 12) ? 16384 : 24576;
    gb = (const char*)((w < 12) ? W1 : W2);
    const int p0 = (w & 3) * 2048 + lane * 16, p1 = p0 + 1024;
    const int r0 = p0 >> 7, c0 = p0 & 127;
    const int r1 = p1 >> 7, c1 = p1 & 127;
    src0 = r0 * 1536 + (c0 ^ ((r0 & 7) << 4));
    src1 = r1 * 1536 + (c1 ^ ((r1 & 7) << 4));
    dst0 = base + p0; dst1 = base + p1; kmul = 128; nld = 2;
  }

  auto stage = [&](int k) {
    char* buf = smem + (k & 1) * BUFSZ;
    gload16(gb + k * kmul + src0, buf + dst0);
    if (nld == 2) gload16(gb + k * kmul + src1, buf + dst1);
  };

  const int mg = w >> 2, nq = w & 3;
  fx4 a1 = fx4{0.f, 0.f, 0.f, 0.f};
  fx4 a2 = fx4{0.f, 0.f, 0.f, 0.f};
  const int xsw = (fr & 7) << 4;            // (mg*16+fr)&7 == fr&7
  const int wr  = nq * 16 + fr;
  const int wsw = (fr & 7) << 4;            // wr&7 == fr&7

  auto compute = [&](int k) {
    const char* cur = smem + (k & 1) * BUFSZ;
    const char* xrb = cur + (mg * 16 + fr) * 256;
#pragma unroll
    for (int ks = 0; ks < 2; ++ks) {
      fx4 xlo = *reinterpret_cast<const fx4*>(xrb + ((ks * 128 + fg * 32) ^ xsw));
      fx4 xhi = *reinterpret_cast<const fx4*>(xrb + ((ks * 128 + fg * 32 + 16) ^ xsw));
      s16x8 xa = cvt8(xlo, xhi);
      const int wo = wr * 128 + ((ks * 64 + fg * 16) ^ wsw);
      s16x8 wf1 = *reinterpret_cast<const s16x8*>(cur + 16384 + wo);
      a1 = mfma16(wf1, xa, a1);
      if (!ISQ) {
        s16x8 wf2 = *reinterpret_cast<const s16x8*>(cur + 24576 + wo);
        a2 = mfma16(wf2, xa, a2);
      }
    }
  };

  stage(0);
  __syncthreads();
#pragma unroll 2
  for (int k = 0; k < NST; ++k) {
    if (k + 1 < NST) stage(k + 1);
    compute(k);
    __syncthreads();
  }

  // epilogue: D[n][m]: n = nq*16+fg*4+r, m = m0 + mg*16 + fr
  const int m  = m0 + mg * 16 + fr;
  const int n0 = nq * 16 + fg * 4;
  fx4 b14 = *reinterpret_cast<const fx4*>(b1 + n0);
  *reinterpret_cast<s16x4*>(O1 + (size_t)m * HD + n0) =
      cvt4(a1[0] + b14[0], a1[1] + b14[1], a1[2] + b14[2], a1[3] + b14[3]);
  if (!ISQ) {
    fx4 b24 = *reinterpret_cast<const fx4*>(b2 + n0);
    const int bidx = m0 >> 10;               // 64 | 1024: no batch straddle
    const int kvp  = (m0 & 1023) + mg * 16 + fr;
#pragma unroll
    for (int r = 0; r < 4; ++r)
      VT[((size_t)(bidx * HD + n0 + r)) * LEN + kvp] =
          (short)pk2(a2[r] + b24[r], 0.f);
  }
}

__global__ __launch_bounds__(1024, 1) void proj_kernel(
    const float* __restrict__ dec, const float* __restrict__ enc,
    const short* __restrict__ wbuf,   // [3][WELEM] bf16: Wq | Wk | Wv
    const float* __restrict__ bq, const float* __restrict__ bk,
    const float* __restrict__ bv,
    short* __restrict__ Qout, short* __restrict__ Kout,
    short* __restrict__ VT)
{
  __shared__ __align__(16) char smem[65536];
  if (blockIdx.x < 256) {
    proj_body<true>(dec, wbuf, nullptr, bq, nullptr,
                    Qout, nullptr, (int)blockIdx.x * 64, smem);
  } else {
    proj_body<false>(enc, wbuf + WELEM, wbuf + 2 * (size_t)WELEM, bk, bv,
                     Kout, VT, ((int)blockIdx.x - 256) * 64, smem);
  }
}

// ---------------------------------------------------------------------------
// Fused flash attention (reverted to the proven r5-r15 form; ~3.5 us).
// 1024 threads = 16 waves = 4 KV-groups x 4 q-waves; K/V LDS-staged per
// group; lane-local softmax; partial combine through LDS overlay.
// ---------------------------------------------------------------------------
__global__ __launch_bounds__(1024, 4) void attn_kernel(
    const short* __restrict__ Q, const short* __restrict__ K,
    const short* __restrict__ VT, float* __restrict__ Out)
{
  __shared__ __align__(16) char smem[110592];
  short (*Kls)[64][72]  = reinterpret_cast<short(*)[64][72]>(smem);
  short (*Vls)[64][72]  = reinterpret_cast<short(*)[64][72]>(smem + 36864);
  short (*Plds)[16][72] = reinterpret_cast<short(*)[16][72]>(smem + 73728);
  float (*HL)[64][68]   = reinterpret_cast<float(*)[64][68]>(smem);
  float2 (*ML)[64]      = reinterpret_cast<float2(*)[64]>(smem + 69632);

  const int t = threadIdx.x, lane = t & 63, w = t >> 6;
  const int g = w >> 2, wl = w & 3;
  const int fr = lane & 15, fg = lane >> 4;
  const int xcd = blockIdx.x & 7;
  const int idx = blockIdx.x >> 3;        // 0..31
  const int b   = xcd + ((idx & 1) << 3);
  const int q0  = (idx >> 1) * 64;
  const int qrow = q0 + wl * 16;

  const short* Qb  = Q  + (size_t)b * LEN * HD;
  const short* Kb  = K  + ((size_t)b * LEN + g * KVQ) * HD;
  const short* VTb = VT + (size_t)b * HD * LEN + g * KVQ;

  s16x8 qa0 = *reinterpret_cast<const s16x8*>(Qb + (size_t)(qrow + fr) * HD + fg * 8);
  s16x8 qa1 = *reinterpret_cast<const s16x8*>(Qb + (size_t)(qrow + fr) * HD + 32 + fg * 8);

  fx4 hacc[4];
#pragma unroll
  for (int c = 0; c < 4; ++c) hacc[c] = fx4{0.f, 0.f, 0.f, 0.f};
  float mrun = -1e30f, lsum = 0.f;
  const float SC = 0.125f * 1.44269504088896340736f;  // 1/sqrt(64) * log2(e)

  const int u = t & 255;
  const int srow = u >> 2;          // 0..63
  const int sch  = (u & 3) * 16;    // short col offset: 0,16,32,48 (32B/lane)

  s16x8 pk0 = *reinterpret_cast<const s16x8*>(Kb + (size_t)srow * HD + sch);
  s16x8 pk1 = *reinterpret_cast<const s16x8*>(Kb + (size_t)srow * HD + sch + 8);
  s16x8 pv0 = *reinterpret_cast<const s16x8*>(VTb + (size_t)srow * LEN + sch);
  s16x8 pv1 = *reinterpret_cast<const s16x8*>(VTb + (size_t)srow * LEN + sch + 8);
  *reinterpret_cast<s16x8*>(&Kls[g][srow][sch])     = pk0;
  *reinterpret_cast<s16x8*>(&Kls[g][srow][sch + 8]) = pk1;
  *reinterpret_cast<s16x8*>(&Vls[g][srow][sch])     = pv0;
  *reinterpret_cast<s16x8*>(&Vls[g][srow][sch + 8]) = pv1;
  __syncthreads();

#pragma unroll
  for (int it = 0; it < KVQ / 64; ++it) {
    if (it + 1 < KVQ / 64) {  // issue next tile's loads before compute
      const int nk = (it + 1) * 64;
      pk0 = *reinterpret_cast<const s16x8*>(Kb + (size_t)(nk + srow) * HD + sch);
      pk1 = *reinterpret_cast<const s16x8*>(Kb + (size_t)(nk + srow) * HD + sch + 8);
      pv0 = *reinterpret_cast<const s16x8*>(VTb + (size_t)srow * LEN + nk + sch);
      pv1 = *reinterpret_cast<const s16x8*>(VTb + (size_t)srow * LEN + nk + sch + 8);
    }
    fx4 sacc[4];
#pragma unroll
    for (int s = 0; s < 4; ++s) {
      s16x8 kf0 = *reinterpret_cast<const s16x8*>(&Kls[g][s * 16 + fr][fg * 8]);
      s16x8 kf1 = *reinterpret_cast<const s16x8*>(&Kls[g][s * 16 + fr][32 + fg * 8]);
      fx4 z = fx4{0.f, 0.f, 0.f, 0.f};
      z = mfma16(kf0, qa0, z);
      sacc[s] = mfma16(kf1, qa1, z);
    }
    float xs[4][4];
    float xm = -1e30f;
#pragma unroll
    for (int s = 0; s < 4; ++s)
#pragma unroll
      for (int r = 0; r < 4; ++r) {
        xs[s][r] = sacc[s][r] * SC;
        xm = fmaxf(xm, xs[s][r]);
      }
    xm = fmaxf(xm, __shfl_xor(xm, 16, 64));
    xm = fmaxf(xm, __shfl_xor(xm, 32, 64));
    const float mn = fmaxf(mrun, xm);
    const float corr = __builtin_amdgcn_exp2f(mrun - mn);
    mrun = mn;
    float ps = 0.f;
#pragma unroll
    for (int s = 0; s < 4; ++s) {
      float p[4];
#pragma unroll
      for (int r = 0; r < 4; ++r) {
        p[r] = __builtin_amdgcn_exp2f(xs[s][r] - mn);
        ps += p[r];
      }
      *reinterpret_cast<s16x4*>(&Plds[w][fr][s * 16 + fg * 4]) =
          cvt4(p[0], p[1], p[2], p[3]);
    }
    ps += __shfl_xor(ps, 16, 64);
    ps += __shfl_xor(ps, 32, 64);
    lsum = lsum * corr + ps;
    __builtin_amdgcn_wave_barrier();
    s16x8 pa0 = *reinterpret_cast<const s16x8*>(&Plds[w][fr][fg * 8]);
    s16x8 pa1 = *reinterpret_cast<const s16x8*>(&Plds[w][fr][32 + fg * 8]);
#pragma unroll
    for (int c = 0; c < 4; ++c) {
      s16x8 vf0 = *reinterpret_cast<const s16x8*>(&Vls[g][c * 16 + fr][fg * 8]);
      s16x8 vf1 = *reinterpret_cast<const s16x8*>(&Vls[g][c * 16 + fr][32 + fg * 8]);
      fx4 h = hacc[c];
#pragma unroll
      for (int r = 0; r < 4; ++r) h[r] *= corr;
      h = mfma16(vf0, pa0, h);
      hacc[c] = mfma16(vf1, pa1, h);
    }
    __syncthreads();  // all waves done reading tile it
    if (it + 1 < KVQ / 64) {
      *reinterpret_cast<s16x8*>(&Kls[g][srow][sch])     = pk0;
      *reinterpret_cast<s16x8*>(&Kls[g][srow][sch + 8]) = pk1;
      *reinterpret_cast<s16x8*>(&Vls[g][srow][sch])     = pv0;
      *reinterpret_cast<s16x8*>(&Vls[g][srow][sch + 8]) = pv1;
    }
    __syncthreads();  // tile it+1 visible
  }
#pragma unroll
  for (int c = 0; c < 4; ++c)
    *reinterpret_cast<fx4*>(&HL[g][wl * 16 + fr][c * 16 + fg * 4]) = hacc[c];
  if (fg == 0) ML[g][wl * 16 + fr] = make_float2(mrun, lsum);
  __syncthreads();
  const int row = t >> 4, d0 = (t & 15) * 4;
  const float2 s0 = ML[0][row], s1 = ML[1][row], s2 = ML[2][row], s3 = ML[3][row];
  const float mm = fmaxf(fmaxf(s0.x, s1.x), fmaxf(s2.x, s3.x));
  const float w0 = __builtin_amdgcn_exp2f(s0.x - mm);
  const float w1 = __builtin_amdgcn_exp2f(s1.x - mm);
  const float w2 = __builtin_amdgcn_exp2f(s2.x - mm);
  const float w3 = __builtin_amdgcn_exp2f(s3.x - mm);
  const float inv = 1.0f / (s0.y * w0 + s1.y * w1 + s2.y * w2 + s3.y * w3);
  fx4 h0 = *reinterpret_cast<const fx4*>(&HL[0][row][d0]);
  fx4 h1 = *reinterpret_cast<const fx4*>(&HL[1][row][d0]);
  fx4 h2 = *reinterpret_cast<const fx4*>(&HL[2][row][d0]);
  fx4 h3 = *reinterpret_cast<const fx4*>(&HL[3][row][d0]);
  fx4 o;
#pragma unroll
  for (int r = 0; r < 4; ++r)
    o[r] = (h0[r] * w0 + h1[r] * w1 + h2[r] * w2 + h3[r] * w3) * inv;
  *reinterpret_cast<fx4*>(Out + ((size_t)b * LEN + q0 + row) * HD + d0) = o;
}

extern "C" void kernel_launch(void* const* d_in, const int* in_sizes, int n_in,
                              void* d_out, int out_size, void* d_ws, size_t ws_size,
                              hipStream_t stream) {
  const float* dec = (const float*)d_in[0];
  const float* enc = (const float*)d_in[1];
  const float* Wq  = (const float*)d_in[2];
  const float* bq  = (const float*)d_in[3];
  const float* Wk  = (const float*)d_in[4];
  const float* bk  = (const float*)d_in[5];
  const float* Wv  = (const float*)d_in[6];
  const float* bv  = (const float*)d_in[7];
  float* out = (float*)d_out;

  short* qws  = (short*)d_ws;                        // [16384,64] bf16
  short* kws  = qws + (size_t)M_TOT * HD;            // [16384,64] bf16
  short* vtws = kws + (size_t)M_TOT * HD;            // [16,64,1024] bf16
  short* wbuf = vtws + (size_t)NB * HD * LEN;        // [3][49152] bf16 weights

  convert_w_kernel<<<(3 * WELEM / 8) / 256, 256, 0, stream>>>(Wq, Wk, Wv, wbuf);
  proj_kernel<<<512, 1024, 0, stream>>>(
      dec, enc, wbuf, bq, bk, bv, qws, kws, vtws);
  attn_kernel<<<NB * (LEN / 64), 1024, 0, stream>>>(qws, kws, vtws, out);
}